// Round 4
// baseline (3329.498 us; speedup 1.0000x reference)
//
#include <hip/hip_runtime.h>
#include <cstdint>
#include <cstddef>

#define CMID 512

typedef __bf16 bf16x8 __attribute__((ext_vector_type(8)));
typedef float  f32x4  __attribute__((ext_vector_type(4)));

__device__ __forceinline__ ushort f2bf(float v) {
  unsigned u = __float_as_uint(v);
  unsigned r = (u + 0x7fffu + ((u >> 16) & 1u)) >> 16;   // RNE
  return (ushort)r;
}

// ---- W [27][Cin][512] f32  ->  wT [27][512][Cin] bf16 ----------------------
__global__ __launch_bounds__(256) void transpose_w_kernel(
    const float* __restrict__ W, ushort* __restrict__ wT, int Cin)
{
  __shared__ float tile[32][33];
  int k = blockIdx.z;
  int ci0 = blockIdx.x * 32, co0 = blockIdx.y * 32;
  int tx = threadIdx.x & 31, ty = threadIdx.x >> 5;
  const float* src = W + ((size_t)k * Cin + ci0) * CMID + co0;
  for (int r = ty; r < 32; r += 8)
    tile[r][tx] = src[(size_t)r * CMID + tx];
  __syncthreads();
  ushort* dst = wT + ((size_t)k * CMID + co0) * Cin + ci0;
  for (int r = ty; r < 32; r += 8)
    dst[(size_t)r * Cin + tx] = f2bf(tile[tx][r]);
}

// ---- center conv (k=13, identity map): plain fp32 stores = accum init -----
__global__ __launch_bounds__(256) void conv_center(
    const ushort* __restrict__ x, const ushort* __restrict__ wT,
    float* __restrict__ out, int n_out, int C_in)
{
  const int k  = 13;
  const int p0 = blockIdx.x * 128;
  const int j0 = blockIdx.y * 128;
  const int t  = threadIdx.x;

  __shared__ ushort A_s[128][72];
  __shared__ ushort B_s[128][72];

  const int lr = t >> 3;
  const int lo = (t & 7) * 8;
  const ushort* wk = wT + ((size_t)k * CMID + j0) * C_in;

  const int lane = t & 63;
  const int wv   = t >> 6;
  const int wm   = (wv & 1) * 64;
  const int wn   = (wv >> 1) * 64;
  const int ml   = lane & 15;
  const int q    = lane >> 4;

  f32x4 acc[4][4] = {};

  for (int kb = 0; kb < C_in; kb += 64) {
#pragma unroll
    for (int i = 0; i < 4; ++i) {
      int row = lr + 32 * i;
      int src = p0 + row; if (src >= n_out) src = n_out - 1;   // clamp (masked at store)
      *(uint4*)&A_s[row][lo] = *(const uint4*)(x + (size_t)src * C_in + kb + lo);
      *(uint4*)&B_s[row][lo] = *(const uint4*)(wk + (size_t)row * C_in + kb + lo);
    }
    __syncthreads();
#pragma unroll
    for (int ks = 0; ks < 2; ++ks) {
      bf16x8 af[4], bb[4];
#pragma unroll
      for (int mt = 0; mt < 4; ++mt)
        af[mt] = *(const bf16x8*)&A_s[wm + mt * 16 + ml][ks * 32 + q * 8];
#pragma unroll
      for (int nt = 0; nt < 4; ++nt)
        bb[nt] = *(const bf16x8*)&B_s[wn + nt * 16 + ml][ks * 32 + q * 8];
#pragma unroll
      for (int mt = 0; mt < 4; ++mt)
#pragma unroll
        for (int nt = 0; nt < 4; ++nt)
          acc[mt][nt] = __builtin_amdgcn_mfma_f32_16x16x32_bf16(
              af[mt], bb[nt], acc[mt][nt], 0, 0, 0);
    }
    __syncthreads();
  }

  // C/D layout: col = lane&15, row = (lane>>4)*4 + reg   [m89-verified]
#pragma unroll
  for (int mt = 0; mt < 4; ++mt) {
#pragma unroll
    for (int r = 0; r < 4; ++r) {
      int o = p0 + wm + mt * 16 + q * 4 + r;
      if (o < n_out) {
        float* orow = out + (size_t)o * CMID + j0 + wn + ml;
#pragma unroll
        for (int nt = 0; nt < 4; ++nt) orow[nt * 16] = acc[mt][nt][r];
      }
    }
  }
}

// ---- off-center scatter conv: Z-MERGED loop over offsets ------------------
// grid (ceil(P/128), 4, G).  Block loops z = gz, gz+G, ... < 26 (k = z+(z>=13)),
// running a full 128x128x Cin GEMM + fp32 atomicAdd epilogue per offset.
// Rationale (round-3 post-mortem): 8-K-iter blocks were latency-bound
// (MfmaUtil 12.5%, VALUBusy 15%, occ 22%) — cold map load + scattered gather
// + scattered atomic epilogue never amortized.  Looping offsets in-block
// overlaps epilogue of k with staging of k+1 and keeps gathered x rows hot.
__global__ __launch_bounds__(256) void conv_scatter(
    const ushort* __restrict__ x, const ushort* __restrict__ wT,
    const int* __restrict__ in_map, const int* __restrict__ out_map,
    float* __restrict__ out, int P, int n_out, int C_in, int G)
{
  const int gz = blockIdx.z;
  const int p0 = blockIdx.x * 128;
  const int j0 = blockIdx.y * 128;
  const int t  = threadIdx.x;

  __shared__ int out_s[128];
  __shared__ int in_s[128];
  __shared__ int anyv;
  __shared__ ushort A_s[128][72];    // pitch 72 (144 B): 16B-aligned, 2-way max
  __shared__ ushort B_s[128][72];

  const int lr = t >> 3;
  const int lo = (t & 7) * 8;
  const int lane = t & 63;
  const int wv   = t >> 6;
  const int wm   = (wv & 1) * 64;
  const int wn   = (wv >> 1) * 64;
  const int ml   = lane & 15;
  const int q    = lane >> 4;

  for (int z = gz; z < 26; z += G) {
    const int k = z + (z >= 13 ? 1 : 0);

    __syncthreads();                 // prev epilogue done reading out_s
    if (t == 0) anyv = 0;
    __syncthreads();
    if (t < 128) {
      int p  = p0 + t;
      int oi = (p < P) ? out_map[(size_t)k * P + p] : n_out;
      int ii = (p < P) ? in_map[(size_t)k * P + p]  : 0;
      out_s[t] = oi; in_s[t] = ii;
      if (oi < n_out) anyv = 1;      // benign race
    }
    __syncthreads();
    if (!anyv) continue;             // block-uniform (pairs prefix-packed)

    const ushort* wk = wT + ((size_t)k * CMID + j0) * C_in;
    f32x4 acc[4][4] = {};

    for (int kb = 0; kb < C_in; kb += 64) {
#pragma unroll
      for (int i = 0; i < 4; ++i) {
        int row = lr + 32 * i;
        *(uint4*)&A_s[row][lo] =
            *(const uint4*)(x + (size_t)in_s[row] * C_in + kb + lo);
        *(uint4*)&B_s[row][lo] =
            *(const uint4*)(wk + (size_t)row * C_in + kb + lo);
      }
      __syncthreads();
#pragma unroll
      for (int ks = 0; ks < 2; ++ks) {
        bf16x8 af[4], bb[4];
#pragma unroll
        for (int mt = 0; mt < 4; ++mt)
          af[mt] = *(const bf16x8*)&A_s[wm + mt * 16 + ml][ks * 32 + q * 8];
#pragma unroll
        for (int nt = 0; nt < 4; ++nt)
          bb[nt] = *(const bf16x8*)&B_s[wn + nt * 16 + ml][ks * 32 + q * 8];
#pragma unroll
        for (int mt = 0; mt < 4; ++mt)
#pragma unroll
          for (int nt = 0; nt < 4; ++nt)
            acc[mt][nt] = __builtin_amdgcn_mfma_f32_16x16x32_bf16(
                af[mt], bb[nt], acc[mt][nt], 0, 0, 0);
      }
      __syncthreads();
    }

    // epilogue: fp32 atomics (round-2 semantics; pk-f16 reverted — it did
    // not reduce FETCH and regressed, likely CAS-lowered)
#pragma unroll
    for (int mt = 0; mt < 4; ++mt) {
#pragma unroll
      for (int r = 0; r < 4; ++r) {
        int o = out_s[wm + mt * 16 + q * 4 + r];
        if (o < n_out) {
          float* orow = out + (size_t)o * CMID + j0 + wn + ml;
#pragma unroll
          for (int nt = 0; nt < 4; ++nt)
            atomicAdd(orow + nt * 16, acc[mt][nt][r]);
        }
      }
    }
  }
}

// ---- BN stats (fp32 accum) ------------------------------------------------
__global__ __launch_bounds__(256) void bn_stats_kernel(
    const float* __restrict__ x, float* __restrict__ stats, int n)
{
  int t = threadIdx.x;
  float s0 = 0.f, q0 = 0.f, s1 = 0.f, q1 = 0.f;
  for (int r = blockIdx.x; r < n; r += gridDim.x) {
    const float* row = x + (size_t)r * CMID;
    float v0 = row[t];
    float v1 = row[t + 256];
    s0 += v0; q0 += v0 * v0;
    s1 += v1; q1 += v1 * v1;
  }
  atomicAdd(&stats[t],        s0);
  atomicAdd(&stats[512 + t],  q0);
  atomicAdd(&stats[t + 256],  s1);
  atomicAdd(&stats[768 + t],  q1);
}

// ---- BN apply + ReLU, fp32 in -> bf16 out ---------------------------------
__global__ __launch_bounds__(256) void bn_apply_cast(
    const float* __restrict__ x, const float* __restrict__ stats,
    const float* __restrict__ gamma, const float* __restrict__ beta,
    ushort* __restrict__ y, long total, float inv_n)
{
  long i = (long)blockIdx.x * 256 + threadIdx.x;
  if (i >= total) return;
  int c = (int)(i & 511);
  float mu  = stats[c] * inv_n;
  float var = stats[512 + c] * inv_n - mu * mu;
  float g   = gamma[c] * rsqrtf(var + 1e-5f);
  float v   = (x[i] - mu) * g + beta[c];
  y[i] = f2bf(v > 0.f ? v : 0.f);
}

// ---- pools (post-ReLU >= 0 -> int-punned atomicMax) -----------------------
__global__ __launch_bounds__(256) void pool_max_bf16(
    const ushort* __restrict__ x, const int* __restrict__ idx,
    float* __restrict__ out, long total)
{
  long i = (long)blockIdx.x * 256 + threadIdx.x;
  if (i >= total) return;
  int r = (int)(i >> 9);
  int c = (int)(i & 511);
  int o = idx[r];
  int bits = ((int)x[i]) << 16;
  atomicMax((int*)(out + (size_t)o * CMID + c), bits);
}

__global__ __launch_bounds__(256) void pool_max_f32(
    const float* __restrict__ x, const int* __restrict__ idx,
    float* __restrict__ out, long total)
{
  long i = (long)blockIdx.x * 256 + threadIdx.x;
  if (i >= total) return;
  int r = (int)(i >> 9);
  int c = (int)(i & 511);
  int o = idx[r];
  atomicMax((int*)(out + (size_t)o * CMID + c), __float_as_int(x[i]));
}

// ---- cast fp32 -> bf16 -----------------------------------------------------
__global__ __launch_bounds__(256) void cast_f32_bf16_kernel(
    const float* __restrict__ in, ushort* __restrict__ out, long n)
{
  long i = (long)blockIdx.x * 256 + threadIdx.x;
  if (i < n) out[i] = f2bf(in[i]);
}

// ---- FC: partial GEMM with K-split ----------------------------------------
__global__ __launch_bounds__(256) void fc_partial(
    const float* __restrict__ x, const float* __restrict__ W,
    float* __restrict__ h, int K, int N, int Kc)
{
  __shared__ float xs[8][1024];
  int t  = threadIdx.x;
  int j  = blockIdx.x * 64 + (t & 63);
  int bg = t >> 6;
  int k0 = blockIdx.y * Kc;
  for (int i = t; i < 8 * Kc; i += 256) {
    int b = i / Kc; int kk = i - b * Kc;
    xs[b][kk] = x[(size_t)b * K + k0 + kk];
  }
  __syncthreads();
  float a0 = 0.f, a1 = 0.f;
  for (int kk = 0; kk < Kc; ++kk) {
    float wv = W[(size_t)(k0 + kk) * N + j];
    a0 += xs[bg][kk] * wv;
    a1 += xs[bg + 4][kk] * wv;
  }
  atomicAdd(&h[(size_t)bg * N + j], a0);
  atomicAdd(&h[(size_t)(bg + 4) * N + j], a1);
}

__global__ __launch_bounds__(256) void bias_relu_kernel(
    float* __restrict__ h, const float* __restrict__ bias, int N)
{
  int i = blockIdx.x * 256 + threadIdx.x;
  if (i >= 8 * N) return;
  float v = h[i] + bias[i % N];
  h[i] = v > 0.f ? v : 0.f;
}

// ---- FC3 -------------------------------------------------------------------
__global__ __launch_bounds__(320) void fc3_kernel(
    const float* __restrict__ x, const float* __restrict__ W,
    const float* __restrict__ bias, float* __restrict__ out)
{
  int t = threadIdx.x;
  int j = t % 40;
  int b = t / 40;
  int kb = blockIdx.x * 128;
  float acc = 0.f;
#pragma unroll 8
  for (int kk = 0; kk < 128; ++kk)
    acc += x[(size_t)b * 4096 + kb + kk] * W[(size_t)(kb + kk) * 40 + j];
  if (blockIdx.x == 0) acc += bias[j];
  atomicAdd(&out[(size_t)b * 40 + j], acc);
}

// ---------------------------------------------------------------------------
extern "C" void kernel_launch(void* const* d_in, const int* in_sizes, int n_in,
                              void* d_out, int out_size, void* d_ws, size_t ws_size,
                              hipStream_t stream)
{
  const float* feats  = (const float*)d_in[0];
  const float* wts[6] = {(const float*)d_in[1], (const float*)d_in[2],
                         (const float*)d_in[3], (const float*)d_in[4],
                         (const float*)d_in[5], (const float*)d_in[6]};
  const float* bn_g   = (const float*)d_in[7];
  const float* bn_b   = (const float*)d_in[8];
  const float* fc1_w  = (const float*)d_in[9];
  const float* fc1_b  = (const float*)d_in[10];
  const float* fc2_w  = (const float*)d_in[11];
  const float* fc2_b  = (const float*)d_in[12];
  const float* fc3_w  = (const float*)d_in[13];
  const float* fc3_b  = (const float*)d_in[14];
  const int* map1_in  = (const int*)d_in[15];
  const int* map1_out = (const int*)d_in[16];
  const int* map2_in  = (const int*)d_in[17];
  const int* map2_out = (const int*)d_in[18];
  const int* pool1_idx = (const int*)d_in[19];
  const int* pool2_idx = (const int*)d_in[20];
  const int* batch_idx = (const int*)d_in[21];

  const int N1 = in_sizes[0] / 256;
  const int P1 = in_sizes[15] / 27;
  const int P2 = in_sizes[17] / 27;
  const int n2 = in_sizes[20];
  const int n3 = in_sizes[21];

  // workspace layout (~126.3 MiB), round-2 proven:
  const size_t MB = (size_t)1 << 20;
  char* wsb = (char*)d_ws;
  float*  accum   = (float*)wsb;                 // 64 MiB fp32 conv accum / pool1 fp32
  ushort* fbuf    = (ushort*)(wsb + 64 * MB);    // 32 MiB bf16 features
  ushort* featsb  = (ushort*)(wsb + 96 * MB);    // 16 MiB bf16 conv1 in; later pool2 f32
  ushort* wTbuf   = (ushort*)(wsb + 112 * MB);   // 13.5 MiB bf16 transposed weights
  float*  stats   = (float*)(wsb + 126 * MB);
  float*  gpooled = stats + 1024;
  float*  h1      = gpooled + 8 * 512;
  float*  h2      = h1 + 8 * 4096;
  float*  pooled2f = (float*)featsb;

  long nf = (long)N1 * 256;
  cast_f32_bf16_kernel<<<(int)((nf + 255) / 256), 256, 0, stream>>>(feats, featsb, nf);

  auto conv = [&](const ushort* xin, const float* w, const int* mi, const int* mo,
                  int P, int nout, int Cin, int G) {
    transpose_w_kernel<<<dim3(Cin / 32, CMID / 32, 27), 256, 0, stream>>>(w, wTbuf, Cin);
    conv_center<<<dim3((nout + 127) / 128, 4, 1), 256, 0, stream>>>(
        xin, wTbuf, accum, nout, Cin);
    conv_scatter<<<dim3((P + 127) / 128, 4, G), 256, 0, stream>>>(
        xin, wTbuf, mi, mo, accum, P, nout, Cin, G);
  };
  auto bn = [&](int layer, int n) {
    hipMemsetAsync(stats, 0, 1024 * sizeof(float), stream);
    bn_stats_kernel<<<256, 256, 0, stream>>>(accum, stats, n);
    long tot = (long)n * CMID;
    bn_apply_cast<<<(int)((tot + 255) / 256), 256, 0, stream>>>(
        accum, stats, bn_g + layer * CMID, bn_b + layer * CMID, fbuf, tot, 1.0f / n);
  };

  // G per level: lvl-1 tiles_x is small (P1 ~ 4-5k) -> G=13 keeps ~1.8k blocks;
  // lvl-2 tiles_x ~ 110-130 -> G=4 gives ~2k blocks, ~7 offsets/block.
  const int G1 = 13, G2 = 4;

  // --- level 1 ---
  conv(featsb, wts[0], map1_in, map1_out, P1, N1, 256, G1); bn(0, N1);
  conv(fbuf,   wts[1], map1_in, map1_out, P1, N1, 512, G1); bn(1, N1);
  conv(fbuf,   wts[2], map1_in, map1_out, P1, N1, 512, G1); bn(2, N1);

  // --- pool 1 ---
  long t1 = (long)N1 * CMID;
  long t2 = (long)n2 * CMID;
  hipMemsetAsync(accum, 0, (size_t)n2 * CMID * sizeof(float), stream);
  pool_max_bf16<<<(int)((t1 + 255) / 256), 256, 0, stream>>>(fbuf, pool1_idx, accum, t1);
  cast_f32_bf16_kernel<<<(int)((t2 + 255) / 256), 256, 0, stream>>>(accum, fbuf, t2);

  // --- level 2 ---
  conv(fbuf, wts[3], map2_in, map2_out, P2, n2, 512, G2); bn(3, n2);
  conv(fbuf, wts[4], map2_in, map2_out, P2, n2, 512, G2); bn(4, n2);
  conv(fbuf, wts[5], map2_in, map2_out, P2, n2, 512, G2); bn(5, n2);

  // --- pool 2 + global max pool ---
  long t3 = (long)n3 * CMID;
  hipMemsetAsync(pooled2f, 0, (size_t)n3 * CMID * sizeof(float), stream);
  pool_max_bf16<<<(int)((t2 + 255) / 256), 256, 0, stream>>>(fbuf, pool2_idx, pooled2f, t2);
  hipMemsetAsync(gpooled, 0, 8 * CMID * sizeof(float), stream);
  pool_max_f32<<<(int)((t3 + 255) / 256), 256, 0, stream>>>(pooled2f, batch_idx, gpooled, t3);

  // --- FC head ---
  hipMemsetAsync(h1, 0, 8 * 4096 * sizeof(float), stream);
  fc_partial<<<dim3(64, 1), 256, 0, stream>>>(gpooled, fc1_w, h1, 512, 4096, 512);
  bias_relu_kernel<<<128, 256, 0, stream>>>(h1, fc1_b, 4096);
  hipMemsetAsync(h2, 0, 8 * 4096 * sizeof(float), stream);
  fc_partial<<<dim3(64, 4), 256, 0, stream>>>(h1, fc2_w, h2, 4096, 4096, 1024);
  bias_relu_kernel<<<128, 256, 0, stream>>>(h2, fc2_b, 4096);
  hipMemsetAsync(d_out, 0, (size_t)out_size * sizeof(float), stream);
  fc3_kernel<<<32, 320, 0, stream>>>(h2, fc3_w, fc3_b, (float*)d_out);
}

// Round 5
// 3068.582 us; speedup vs baseline: 1.0850x; 1.0850x over previous
//
#include <hip/hip_runtime.h>
#include <cstdint>
#include <cstddef>

#define CMID 512

typedef __bf16 bf16x8 __attribute__((ext_vector_type(8)));
typedef float  f32x4  __attribute__((ext_vector_type(4)));

__device__ __forceinline__ ushort f2bf(float v) {
  unsigned u = __float_as_uint(v);
  unsigned r = (u + 0x7fffu + ((u >> 16) & 1u)) >> 16;   // RNE
  return (ushort)r;
}

// ---- W [27][Cin][512] f32  ->  wT [27][512][Cin] bf16 ----------------------
__global__ __launch_bounds__(256) void transpose_w_kernel(
    const float* __restrict__ W, ushort* __restrict__ wT, int Cin)
{
  __shared__ float tile[32][33];
  int k = blockIdx.z;
  int ci0 = blockIdx.x * 32, co0 = blockIdx.y * 32;
  int tx = threadIdx.x & 31, ty = threadIdx.x >> 5;
  const float* src = W + ((size_t)k * Cin + ci0) * CMID + co0;
  for (int r = ty; r < 32; r += 8)
    tile[r][tx] = src[(size_t)r * CMID + tx];
  __syncthreads();
  ushort* dst = wT + ((size_t)k * CMID + co0) * Cin + ci0;
  for (int r = ty; r < 32; r += 8)
    dst[(size_t)r * Cin + tx] = f2bf(tile[tx][r]);
}

// ---- build inverse kernel map: inv[k][o] = in_idx (or -1) -----------------
__global__ __launch_bounds__(256) void build_inv_kernel(
    const int* __restrict__ in_map, const int* __restrict__ out_map,
    int* __restrict__ inv, int P, int n_out)
{
  int i = blockIdx.x * 256 + threadIdx.x;
  if (i >= 27 * P) return;
  int o = out_map[i];
  if (o < n_out) inv[(size_t)(i / P) * n_out + o] = in_map[i];
}

// ---- OUTPUT-STATIONARY conv (level 2): no atomics -------------------------
// grid (ceil(n_out/128), 4).  Block owns a 128x128 C-tile; loops k=0..26,
// gathers A rows via inv[k][o] (zero row if -1), accumulates all 27 offsets
// into persistent acc registers, stores each output element ONCE (plain fp32).
// Kills the 1.37 GB/dispatch scattered-atomic RMW traffic that capped rounds
// 2-4 at ~2.4 TB/s.  216 K-iters/block amortizes startup.
__global__ __launch_bounds__(256) void conv_os(
    const ushort* __restrict__ x, const ushort* __restrict__ wT,
    const int* __restrict__ inv, float* __restrict__ out, int n_out, int C_in)
{
  const int o0 = blockIdx.x * 128;
  const int j0 = blockIdx.y * 128;
  const int t  = threadIdx.x;

  __shared__ int in_s[128];
  __shared__ ushort A_s[128][72];    // pitch 72 (144 B): 16B-aligned b128
  __shared__ ushort B_s[128][72];

  const int lr = t >> 3;
  const int lo = (t & 7) * 8;
  const int lane = t & 63;
  const int wv   = t >> 6;
  const int wm   = (wv & 1) * 64;
  const int wn   = (wv >> 1) * 64;
  const int ml   = lane & 15;
  const int q    = lane >> 4;

  f32x4 acc[4][4] = {};

  for (int k = 0; k < 27; ++k) {
    if (t < 128) {
      int o = o0 + t;
      in_s[t] = (o < n_out) ? inv[(size_t)k * n_out + o] : -1;
    }
    __syncthreads();
    const ushort* wk = wT + ((size_t)k * CMID + j0) * C_in;

    for (int kb = 0; kb < C_in; kb += 64) {
#pragma unroll
      for (int i = 0; i < 4; ++i) {
        int row = lr + 32 * i;
        int src = in_s[row];
        uint4 av = make_uint4(0u, 0u, 0u, 0u);
        if (src >= 0)
          av = *(const uint4*)(x + (size_t)src * C_in + kb + lo);
        *(uint4*)&A_s[row][lo] = av;
        *(uint4*)&B_s[row][lo] = *(const uint4*)(wk + (size_t)row * C_in + kb + lo);
      }
      __syncthreads();
#pragma unroll
      for (int ks = 0; ks < 2; ++ks) {
        bf16x8 af[4], bb[4];
#pragma unroll
        for (int mt = 0; mt < 4; ++mt)
          af[mt] = *(const bf16x8*)&A_s[wm + mt * 16 + ml][ks * 32 + q * 8];
#pragma unroll
        for (int nt = 0; nt < 4; ++nt)
          bb[nt] = *(const bf16x8*)&B_s[wn + nt * 16 + ml][ks * 32 + q * 8];
#pragma unroll
        for (int mt = 0; mt < 4; ++mt)
#pragma unroll
          for (int nt = 0; nt < 4; ++nt)
            acc[mt][nt] = __builtin_amdgcn_mfma_f32_16x16x32_bf16(
                af[mt], bb[nt], acc[mt][nt], 0, 0, 0);
      }
      __syncthreads();               // also guards in_s overwrite next k
    }
  }

  // C/D layout: col = lane&15, row = (lane>>4)*4 + reg   [m89-verified]
#pragma unroll
  for (int mt = 0; mt < 4; ++mt) {
#pragma unroll
    for (int r = 0; r < 4; ++r) {
      int o = o0 + wm + mt * 16 + q * 4 + r;
      if (o < n_out) {
        float* orow = out + (size_t)o * CMID + j0 + wn + ml;
#pragma unroll
        for (int nt = 0; nt < 4; ++nt) orow[nt * 16] = acc[mt][nt][r];
      }
    }
  }
}

// ---- center conv (level 1, k=13 identity): plain stores = accum init ------
__global__ __launch_bounds__(256) void conv_center(
    const ushort* __restrict__ x, const ushort* __restrict__ wT,
    float* __restrict__ out, int n_out, int C_in)
{
  const int k  = 13;
  const int p0 = blockIdx.x * 128;
  const int j0 = blockIdx.y * 128;
  const int t  = threadIdx.x;

  __shared__ ushort A_s[128][72];
  __shared__ ushort B_s[128][72];

  const int lr = t >> 3;
  const int lo = (t & 7) * 8;
  const ushort* wk = wT + ((size_t)k * CMID + j0) * C_in;

  const int lane = t & 63;
  const int wv   = t >> 6;
  const int wm   = (wv & 1) * 64;
  const int wn   = (wv >> 1) * 64;
  const int ml   = lane & 15;
  const int q    = lane >> 4;

  f32x4 acc[4][4] = {};

  for (int kb = 0; kb < C_in; kb += 64) {
#pragma unroll
    for (int i = 0; i < 4; ++i) {
      int row = lr + 32 * i;
      int src = p0 + row; if (src >= n_out) src = n_out - 1;
      *(uint4*)&A_s[row][lo] = *(const uint4*)(x + (size_t)src * C_in + kb + lo);
      *(uint4*)&B_s[row][lo] = *(const uint4*)(wk + (size_t)row * C_in + kb + lo);
    }
    __syncthreads();
#pragma unroll
    for (int ks = 0; ks < 2; ++ks) {
      bf16x8 af[4], bb[4];
#pragma unroll
      for (int mt = 0; mt < 4; ++mt)
        af[mt] = *(const bf16x8*)&A_s[wm + mt * 16 + ml][ks * 32 + q * 8];
#pragma unroll
      for (int nt = 0; nt < 4; ++nt)
        bb[nt] = *(const bf16x8*)&B_s[wn + nt * 16 + ml][ks * 32 + q * 8];
#pragma unroll
      for (int mt = 0; mt < 4; ++mt)
#pragma unroll
        for (int nt = 0; nt < 4; ++nt)
          acc[mt][nt] = __builtin_amdgcn_mfma_f32_16x16x32_bf16(
              af[mt], bb[nt], acc[mt][nt], 0, 0, 0);
    }
    __syncthreads();
  }

#pragma unroll
  for (int mt = 0; mt < 4; ++mt) {
#pragma unroll
    for (int r = 0; r < 4; ++r) {
      int o = p0 + wm + mt * 16 + q * 4 + r;
      if (o < n_out) {
        float* orow = out + (size_t)o * CMID + j0 + wn + ml;
#pragma unroll
        for (int nt = 0; nt < 4; ++nt) orow[nt * 16] = acc[mt][nt][r];
      }
    }
  }
}

// ---- level-1 off-center scatter conv (round-2 z-split: one offset/block) --
__global__ __launch_bounds__(256) void conv_scatter(
    const ushort* __restrict__ x, const ushort* __restrict__ wT,
    const int* __restrict__ in_map, const int* __restrict__ out_map,
    float* __restrict__ out, int P, int n_out, int C_in)
{
  const int k  = (int)blockIdx.z + (blockIdx.z >= 13 ? 1 : 0);
  const int p0 = blockIdx.x * 128;
  const int j0 = blockIdx.y * 128;
  const int t  = threadIdx.x;

  __shared__ int out_s[128];
  __shared__ int in_s[128];
  __shared__ int anyv;
  __shared__ ushort A_s[128][72];
  __shared__ ushort B_s[128][72];

  if (t == 0) anyv = 0;
  __syncthreads();
  if (t < 128) {
    int p  = p0 + t;
    int oi = (p < P) ? out_map[(size_t)k * P + p] : n_out;
    int ii = (p < P) ? in_map[(size_t)k * P + p]  : 0;
    out_s[t] = oi; in_s[t] = ii;
    if (oi < n_out) anyv = 1;
  }
  __syncthreads();
  if (!anyv) return;

  const int lr = t >> 3;
  const int lo = (t & 7) * 8;
  const int lane = t & 63;
  const int wv   = t >> 6;
  const int wm   = (wv & 1) * 64;
  const int wn   = (wv >> 1) * 64;
  const int ml   = lane & 15;
  const int q    = lane >> 4;

  const ushort* wk = wT + ((size_t)k * CMID + j0) * C_in;
  f32x4 acc[4][4] = {};

  for (int kb = 0; kb < C_in; kb += 64) {
#pragma unroll
    for (int i = 0; i < 4; ++i) {
      int row = lr + 32 * i;
      *(uint4*)&A_s[row][lo] = *(const uint4*)(x + (size_t)in_s[row] * C_in + kb + lo);
      *(uint4*)&B_s[row][lo] = *(const uint4*)(wk + (size_t)row * C_in + kb + lo);
    }
    __syncthreads();
#pragma unroll
    for (int ks = 0; ks < 2; ++ks) {
      bf16x8 af[4], bb[4];
#pragma unroll
      for (int mt = 0; mt < 4; ++mt)
        af[mt] = *(const bf16x8*)&A_s[wm + mt * 16 + ml][ks * 32 + q * 8];
#pragma unroll
      for (int nt = 0; nt < 4; ++nt)
        bb[nt] = *(const bf16x8*)&B_s[wn + nt * 16 + ml][ks * 32 + q * 8];
#pragma unroll
      for (int mt = 0; mt < 4; ++mt)
#pragma unroll
        for (int nt = 0; nt < 4; ++nt)
          acc[mt][nt] = __builtin_amdgcn_mfma_f32_16x16x32_bf16(
              af[mt], bb[nt], acc[mt][nt], 0, 0, 0);
    }
    __syncthreads();
  }

#pragma unroll
  for (int mt = 0; mt < 4; ++mt) {
#pragma unroll
    for (int r = 0; r < 4; ++r) {
      int o = out_s[wm + mt * 16 + q * 4 + r];
      if (o < n_out) {
        float* orow = out + (size_t)o * CMID + j0 + wn + ml;
#pragma unroll
        for (int nt = 0; nt < 4; ++nt)
          atomicAdd(orow + nt * 16, acc[mt][nt][r]);
      }
    }
  }
}

// ---- BN stats (fp32 accum) ------------------------------------------------
__global__ __launch_bounds__(256) void bn_stats_kernel(
    const float* __restrict__ x, float* __restrict__ stats, int n)
{
  int t = threadIdx.x;
  float s0 = 0.f, q0 = 0.f, s1 = 0.f, q1 = 0.f;
  for (int r = blockIdx.x; r < n; r += gridDim.x) {
    const float* row = x + (size_t)r * CMID;
    float v0 = row[t];
    float v1 = row[t + 256];
    s0 += v0; q0 += v0 * v0;
    s1 += v1; q1 += v1 * v1;
  }
  atomicAdd(&stats[t],        s0);
  atomicAdd(&stats[512 + t],  q0);
  atomicAdd(&stats[t + 256],  s1);
  atomicAdd(&stats[768 + t],  q1);
}

// ---- BN apply + ReLU, fp32 in -> bf16 out ---------------------------------
__global__ __launch_bounds__(256) void bn_apply_cast(
    const float* __restrict__ x, const float* __restrict__ stats,
    const float* __restrict__ gamma, const float* __restrict__ beta,
    ushort* __restrict__ y, long total, float inv_n)
{
  long i = (long)blockIdx.x * 256 + threadIdx.x;
  if (i >= total) return;
  int c = (int)(i & 511);
  float mu  = stats[c] * inv_n;
  float var = stats[512 + c] * inv_n - mu * mu;
  float g   = gamma[c] * rsqrtf(var + 1e-5f);
  float v   = (x[i] - mu) * g + beta[c];
  y[i] = f2bf(v > 0.f ? v : 0.f);
}

// ---- pools (post-ReLU >= 0 -> int-punned atomicMax) -----------------------
__global__ __launch_bounds__(256) void pool_max_bf16(
    const ushort* __restrict__ x, const int* __restrict__ idx,
    float* __restrict__ out, long total)
{
  long i = (long)blockIdx.x * 256 + threadIdx.x;
  if (i >= total) return;
  int r = (int)(i >> 9);
  int c = (int)(i & 511);
  int o = idx[r];
  int bits = ((int)x[i]) << 16;
  atomicMax((int*)(out + (size_t)o * CMID + c), bits);
}

__global__ __launch_bounds__(256) void pool_max_f32(
    const float* __restrict__ x, const int* __restrict__ idx,
    float* __restrict__ out, long total)
{
  long i = (long)blockIdx.x * 256 + threadIdx.x;
  if (i >= total) return;
  int r = (int)(i >> 9);
  int c = (int)(i & 511);
  int o = idx[r];
  atomicMax((int*)(out + (size_t)o * CMID + c), __float_as_int(x[i]));
}

// ---- cast fp32 -> bf16 -----------------------------------------------------
__global__ __launch_bounds__(256) void cast_f32_bf16_kernel(
    const float* __restrict__ in, ushort* __restrict__ out, long n)
{
  long i = (long)blockIdx.x * 256 + threadIdx.x;
  if (i < n) out[i] = f2bf(in[i]);
}

// ---- FC: partial GEMM with K-split ----------------------------------------
__global__ __launch_bounds__(256) void fc_partial(
    const float* __restrict__ x, const float* __restrict__ W,
    float* __restrict__ h, int K, int N, int Kc)
{
  __shared__ float xs[8][1024];
  int t  = threadIdx.x;
  int j  = blockIdx.x * 64 + (t & 63);
  int bg = t >> 6;
  int k0 = blockIdx.y * Kc;
  for (int i = t; i < 8 * Kc; i += 256) {
    int b = i / Kc; int kk = i - b * Kc;
    xs[b][kk] = x[(size_t)b * K + k0 + kk];
  }
  __syncthreads();
  float a0 = 0.f, a1 = 0.f;
  for (int kk = 0; kk < Kc; ++kk) {
    float wv = W[(size_t)(k0 + kk) * N + j];
    a0 += xs[bg][kk] * wv;
    a1 += xs[bg + 4][kk] * wv;
  }
  atomicAdd(&h[(size_t)bg * N + j], a0);
  atomicAdd(&h[(size_t)(bg + 4) * N + j], a1);
}

__global__ __launch_bounds__(256) void bias_relu_kernel(
    float* __restrict__ h, const float* __restrict__ bias, int N)
{
  int i = blockIdx.x * 256 + threadIdx.x;
  if (i >= 8 * N) return;
  float v = h[i] + bias[i % N];
  h[i] = v > 0.f ? v : 0.f;
}

// ---- FC3 -------------------------------------------------------------------
__global__ __launch_bounds__(320) void fc3_kernel(
    const float* __restrict__ x, const float* __restrict__ W,
    const float* __restrict__ bias, float* __restrict__ out)
{
  int t = threadIdx.x;
  int j = t % 40;
  int b = t / 40;
  int kb = blockIdx.x * 128;
  float acc = 0.f;
#pragma unroll 8
  for (int kk = 0; kk < 128; ++kk)
    acc += x[(size_t)b * 4096 + kb + kk] * W[(size_t)(kb + kk) * 40 + j];
  if (blockIdx.x == 0) acc += bias[j];
  atomicAdd(&out[(size_t)b * 40 + j], acc);
}

// ---------------------------------------------------------------------------
extern "C" void kernel_launch(void* const* d_in, const int* in_sizes, int n_in,
                              void* d_out, int out_size, void* d_ws, size_t ws_size,
                              hipStream_t stream)
{
  const float* feats  = (const float*)d_in[0];
  const float* wts[6] = {(const float*)d_in[1], (const float*)d_in[2],
                         (const float*)d_in[3], (const float*)d_in[4],
                         (const float*)d_in[5], (const float*)d_in[6]};
  const float* bn_g   = (const float*)d_in[7];
  const float* bn_b   = (const float*)d_in[8];
  const float* fc1_w  = (const float*)d_in[9];
  const float* fc1_b  = (const float*)d_in[10];
  const float* fc2_w  = (const float*)d_in[11];
  const float* fc2_b  = (const float*)d_in[12];
  const float* fc3_w  = (const float*)d_in[13];
  const float* fc3_b  = (const float*)d_in[14];
  const int* map1_in  = (const int*)d_in[15];
  const int* map1_out = (const int*)d_in[16];
  const int* map2_in  = (const int*)d_in[17];
  const int* map2_out = (const int*)d_in[18];
  const int* pool1_idx = (const int*)d_in[19];
  const int* pool2_idx = (const int*)d_in[20];
  const int* batch_idx = (const int*)d_in[21];

  const int N1 = in_sizes[0] / 256;
  const int P1 = in_sizes[15] / 27;
  const int P2 = in_sizes[17] / 27;
  const int n2 = in_sizes[20];
  const int n3 = in_sizes[21];

  // workspace layout (~126.3 MiB used of >=128):
  //  [0,64)    accum fp32 (N1 x 512) / pool1 target
  //  [64,96)   fbuf bf16 features (post-BN)
  //  [96,112)  featsb bf16 conv1 input; later: pooled2f (fp32, <=8.5 MB)
  //            + inv2 (27 x n2 ints, ~2.3 MB) at +9 MiB — both live only
  //            after featsb is dead (post-conv1 / post-pool1)
  //  [112,126) wTbuf bf16 transposed weights
  //  [126,..)  stats + FC scratch
  const size_t MB = (size_t)1 << 20;
  char* wsb = (char*)d_ws;
  float*  accum   = (float*)wsb;
  ushort* fbuf    = (ushort*)(wsb + 64 * MB);
  ushort* featsb  = (ushort*)(wsb + 96 * MB);
  int*    inv2    = (int*)(wsb + 105 * MB);
  ushort* wTbuf   = (ushort*)(wsb + 112 * MB);
  float*  stats   = (float*)(wsb + 126 * MB);
  float*  gpooled = stats + 1024;
  float*  h1      = gpooled + 8 * 512;
  float*  h2      = h1 + 8 * 4096;
  float*  pooled2f = (float*)featsb;

  long nf = (long)N1 * 256;
  cast_f32_bf16_kernel<<<(int)((nf + 255) / 256), 256, 0, stream>>>(feats, featsb, nf);

  // level-1 conv: center (plain stores, inits accum) + 26 scatter offsets
  auto conv1 = [&](const ushort* xin, const float* w, int Cin) {
    transpose_w_kernel<<<dim3(Cin / 32, CMID / 32, 27), 256, 0, stream>>>(w, wTbuf, Cin);
    conv_center<<<dim3((N1 + 127) / 128, 4, 1), 256, 0, stream>>>(
        xin, wTbuf, accum, N1, Cin);
    conv_scatter<<<dim3((P1 + 127) / 128, 4, 26), 256, 0, stream>>>(
        xin, wTbuf, map1_in, map1_out, accum, P1, N1, Cin);
  };
  // level-2 conv: output-stationary, no atomics
  auto conv2 = [&](const ushort* xin, const float* w) {
    transpose_w_kernel<<<dim3(512 / 32, CMID / 32, 27), 256, 0, stream>>>(w, wTbuf, 512);
    conv_os<<<dim3((n2 + 127) / 128, 4, 1), 256, 0, stream>>>(
        xin, wTbuf, inv2, accum, n2, 512);
  };
  auto bn = [&](int layer, int n) {
    hipMemsetAsync(stats, 0, 1024 * sizeof(float), stream);
    bn_stats_kernel<<<256, 256, 0, stream>>>(accum, stats, n);
    long tot = (long)n * CMID;
    bn_apply_cast<<<(int)((tot + 255) / 256), 256, 0, stream>>>(
        accum, stats, bn_g + layer * CMID, bn_b + layer * CMID, fbuf, tot, 1.0f / n);
  };

  // --- level 1 ---
  conv1(featsb, wts[0], 256); bn(0, N1);
  conv1(fbuf,   wts[1], 512); bn(1, N1);
  conv1(fbuf,   wts[2], 512); bn(2, N1);

  // --- pool 1: fbuf(N1) -> accum(n2, fp32) -> fbuf bf16 ---
  long t1 = (long)N1 * CMID;
  long t2 = (long)n2 * CMID;
  hipMemsetAsync(accum, 0, (size_t)n2 * CMID * sizeof(float), stream);
  pool_max_bf16<<<(int)((t1 + 255) / 256), 256, 0, stream>>>(fbuf, pool1_idx, accum, t1);
  cast_f32_bf16_kernel<<<(int)((t2 + 255) / 256), 256, 0, stream>>>(accum, fbuf, t2);

  // --- build level-2 inverse map (once; reused by all 3 convs) ---
  hipMemsetAsync(inv2, 0xFF, (size_t)27 * n2 * sizeof(int), stream);
  build_inv_kernel<<<(27 * P2 + 255) / 256, 256, 0, stream>>>(
      map2_in, map2_out, inv2, P2, n2);

  // --- level 2 (output-stationary) ---
  conv2(fbuf, wts[3]); bn(3, n2);
  conv2(fbuf, wts[4]); bn(4, n2);
  conv2(fbuf, wts[5]); bn(5, n2);

  // --- pool 2 + global max pool ---
  long t3 = (long)n3 * CMID;
  hipMemsetAsync(pooled2f, 0, (size_t)n3 * CMID * sizeof(float), stream);
  pool_max_bf16<<<(int)((t2 + 255) / 256), 256, 0, stream>>>(fbuf, pool2_idx, pooled2f, t2);
  hipMemsetAsync(gpooled, 0, 8 * CMID * sizeof(float), stream);
  pool_max_f32<<<(int)((t3 + 255) / 256), 256, 0, stream>>>(pooled2f, batch_idx, gpooled, t3);

  // --- FC head ---
  hipMemsetAsync(h1, 0, 8 * 4096 * sizeof(float), stream);
  fc_partial<<<dim3(64, 1), 256, 0, stream>>>(gpooled, fc1_w, h1, 512, 4096, 512);
  bias_relu_kernel<<<128, 256, 0, stream>>>(h1, fc1_b, 4096);
  hipMemsetAsync(h2, 0, 8 * 4096 * sizeof(float), stream);
  fc_partial<<<dim3(64, 4), 256, 0, stream>>>(h1, fc2_w, h2, 4096, 4096, 1024);
  bias_relu_kernel<<<128, 256, 0, stream>>>(h2, fc2_b, 4096);
  hipMemsetAsync(d_out, 0, (size_t)out_size * sizeof(float), stream);
  fc3_kernel<<<32, 320, 0, stream>>>(h2, fc3_w, fc3_b, (float*)d_out);
}